// Round 5
// baseline (675.877 us; speedup 1.0000x reference)
//
#include <hip/hip_runtime.h>

#define N_MET 100000
#define N_RXN 50000
#define E_SUB 2000000
#define E_ALL 4000000
#define MSG_DIM 16
#define HIDDEN 32

// dxdt-side binning: buckets of 256 metabolites, 8192-edge tiles.
#define NBKT_A 391            // ceil(100000/256)
#define NB_ALL 489            // ceil(4000000/8192)
// v-side binning: buckets of 64 reactions, 8192-edge tiles.
#define NBKT_S 782            // ceil(50000/64)
#define NB_SUB 245            // ceil(2000000/8192)

// HW model (R1-R17): scattered GLOBAL atomics = ~19-20 G ops/s wall.
// R13: per-thread sequential LDS-atomic chains = latency-bound. R14/R15:
// counting-sort + coalesced run copy-out. R16: LDS-size changes (51->35KB)
// did NOT move occupancy (37%) or duration -> occupancy is not LDS-limited;
// the barrier-locked 4-phase sort loop itself is the overhead (rank-atomic
// latency + single-wave scan + lockstep stalls; VALUBusy 50%).
// R17 (this round): delete the in-block sort. Half-wave = contiguous edge
// segment; all 32 lanes process the SAME edge (lane = hidden dim j);
// broadcast global load (L1 lines reused 8x), one fire-and-forget
// ds_add_f32 per edge-half into sth[r*33+j] (banks (r+j)%32, <=2-way =
// free), count as a free "33rd hidden unit" at sth[r*33+32]. NO main-loop
// barriers -> waves fully independent. W2m folded into per-rxn epilogue.

__device__ __forceinline__ float fast_tanh(float x) {
    // tanh(x) = sign(x) * (1 - 2/(e^{2|x|}+1)); branch-free, v_exp+v_rcp.
    const float ax = fabsf(x);
    const float e = __expf(2.0f * ax);
    const float t = 1.0f - 2.0f * __builtin_amdgcn_rcpf(e + 1.0f);
    return copysignf(t, x);
}

// ---- generic scans -----------------------------------------------------------

__global__ __launch_bounds__(256) void scan_cols_kernel(
    int* __restrict__ hist, int* __restrict__ tot, int nblocks, int nbkt)
{
    __shared__ int wsum[4];
    const int b = blockIdx.x;
    const int t = threadIdx.x, lane = t & 63, w = t >> 6;
    int carry = 0;
    for (int basei = 0; basei < nblocks; basei += 256) {
        const int bk = basei + t;
        const int val = (bk < nblocks) ? hist[(size_t)bk * nbkt + b] : 0;
        int x = val;
#pragma unroll
        for (int off = 1; off < 64; off <<= 1) {
            const int y = __shfl_up(x, off);
            if (lane >= off) x += y;
        }
        if (lane == 63) wsum[w] = x;
        __syncthreads();
        if (w == 0) {
            int s = (lane < 4) ? wsum[lane] : 0;
#pragma unroll
            for (int off = 1; off < 4; off <<= 1) {
                const int y = __shfl_up(s, off);
                if (lane >= off) s += y;
            }
            if (lane < 4) wsum[lane] = s;
        }
        __syncthreads();
        const int excl = carry + ((w > 0) ? wsum[w - 1] : 0) + x - val;
        if (bk < nblocks) hist[(size_t)bk * nbkt + b] = excl;
        carry += wsum[3];
        __syncthreads();
    }
    if (t == 0) tot[b] = carry;
}

__global__ __launch_bounds__(256) void scan_base_kernel(
    const int* __restrict__ tot, int* __restrict__ base, int nbkt)
{
    __shared__ int wsum[4];
    const int t = threadIdx.x, lane = t & 63, w = t >> 6;
    int carry = 0;
    for (int basei = 0; basei < nbkt; basei += 256) {
        const int i = basei + t;
        const int val = (i < nbkt) ? tot[i] : 0;
        int x = val;
#pragma unroll
        for (int off = 1; off < 64; off <<= 1) {
            const int y = __shfl_up(x, off);
            if (lane >= off) x += y;
        }
        if (lane == 63) wsum[w] = x;
        __syncthreads();
        if (w == 0) {
            int s = (lane < 4) ? wsum[lane] : 0;
#pragma unroll
            for (int off = 1; off < 4; off <<= 1) {
                const int y = __shfl_up(s, off);
                if (lane >= off) s += y;
            }
            if (lane < 4) wsum[lane] = s;
        }
        __syncthreads();
        const int excl = carry + ((w > 0) ? wsum[w - 1] : 0) + x - val;
        if (i < nbkt) base[i] = excl;
        carry += wsum[3];
        __syncthreads();
    }
}

// ---- Phase 1: v via reaction-bucket binning ---------------------------------

__global__ __launch_bounds__(1024) void hist_sub_kernel(
    const int* __restrict__ rxn_sub, int* __restrict__ hist)
{
    __shared__ int hb[NBKT_S];
    const int t = threadIdx.x, bk = blockIdx.x;
    for (int i = t; i < NBKT_S; i += 1024) hb[i] = 0;
    __syncthreads();
#pragma unroll
    for (int k = 0; k < 2; ++k) {
        const int i = bk * 2048 + (k << 10) + t;
        if (i < E_SUB / 4) {
            const int4 r = ((const int4*)rxn_sub)[i];
            atomicAdd(&hb[r.x >> 6], 1);
            atomicAdd(&hb[r.y >> 6], 1);
            atomicAdd(&hb[r.z >> 6], 1);
            atomicAdd(&hb[r.w >> 6], 1);
        }
    }
    __syncthreads();
    for (int i2 = t; i2 < NBKT_S; i2 += 1024) hist[bk * NBKT_S + i2] = hb[i2];
}

// counting-sort scatter (8192-edge tile): rank via LDS atomic, single-wave
// scan, LDS sort, then per-bucket runs copied out as contiguous bursts.
// payload {x, s'} where s' carries rxn&63 in its low 6 mantissa bits.
__global__ __launch_bounds__(1024) void scatter_bin_sub_kernel(
    const float* __restrict__ x_met, const float* __restrict__ sto_sub,
    const int* __restrict__ met_sub, const int* __restrict__ rxn_sub,
    const int* __restrict__ hist, const int* __restrict__ base,
    float2* __restrict__ pxs)
{
    __shared__ float2 se[8192];          // sorted payloads (64 KB)
    __shared__ int cnt[NBKT_S];
    __shared__ int loff[NBKT_S + 1];
    __shared__ int goff[NBKT_S];
    const int t = threadIdx.x, bk = blockIdx.x;
    for (int i = t; i < NBKT_S; i += 1024) {
        cnt[i] = 0;
        goff[i] = hist[bk * NBKT_S + i] + base[i];
    }
    __syncthreads();

    float2 pay[8]; int meta[8];
    const int e0 = bk * 8192;
#pragma unroll
    for (int k = 0; k < 8; ++k) {
        const int e = e0 + (k << 10) + t;
        if (e < E_SUB) {
            const int r = rxn_sub[e];
            const float x = x_met[met_sub[e]];
            const int sb = (__float_as_int(sto_sub[e]) & ~63) | (r & 63);
            pay[k] = make_float2(x, __int_as_float(sb));
            const int q = r >> 6;
            meta[k] = (atomicAdd(&cnt[q], 1) << 10) | q;   // rank<=8191, q<1024
        } else meta[k] = -1;
    }
    __syncthreads();

    // single-wave exclusive scan of cnt[782] -> loff (no barriers needed)
    if (t < 64) {
        int carry = 0;
        for (int bb = 0; bb < NBKT_S; bb += 64) {
            const int idx = bb + t;
            const int val = (idx < NBKT_S) ? cnt[idx] : 0;
            int x = val;
#pragma unroll
            for (int off = 1; off < 64; off <<= 1) {
                const int y = __shfl_up(x, off);
                if (t >= off) x += y;
            }
            if (idx < NBKT_S) loff[idx] = carry + x - val;
            carry += __shfl(x, 63);
        }
        if (t == 0) loff[NBKT_S] = carry;
    }
    __syncthreads();

#pragma unroll
    for (int k = 0; k < 8; ++k) {
        if (meta[k] >= 0)
            se[loff[meta[k] & 1023] + (meta[k] >> 10)] = pay[k];
    }
    __syncthreads();

    // copy-out: wave w handles runs q = w, w+16, ... (coalesced bursts)
    const int w = t >> 6, lane = t & 63;
    for (int q = w; q < NBKT_S; q += 16) {
        const int s = loff[q], lenq = loff[q + 1] - s, d = goff[q];
        for (int i = lane; i < lenq; i += 64)
            pxs[d + i] = se[s + i];
    }
}

// one block (512 thr, 8 waves) per bucket of 64 reactions. NO SORT, NO
// main-loop barriers: half-wave k (k=0..15) owns a contiguous edge segment;
// all 32 lanes process the SAME edge (lane = hidden dim j). Broadcast
// global load (sequential -> L1 line reuse 8x), one ds_add_f32 per
// edge-half into sth[r*33+j]; per-rxn count = "33rd hidden unit" at
// sth[r*33+32] (lane 0). Loads software-pipelined 4 deep (clamped).
// Epilogue: W2m matmul (linearity of segment_sum) + rate MLP.
__global__ __launch_bounds__(512, 8) void bucket_msg_kernel(
    const float2* __restrict__ pxs,
    const int* __restrict__ base, const int* __restrict__ tot,
    const float* __restrict__ W1m, const float* __restrict__ b1m,
    const float* __restrict__ W2m, const float* __restrict__ b2m,
    const float* __restrict__ W1r, const float* __restrict__ b1r,
    const float* __restrict__ W2r, const float* __restrict__ b2r,
    float* __restrict__ v)
{
    __shared__ float  sth[64 * 33];          // [rxn][j=0..31 tanh sums, 32=cnt]
    __shared__ float  sW2m[HIDDEN * MSG_DIM];
    __shared__ float  sb2m[MSG_DIM];
    __shared__ float  sW1r[MSG_DIM * HIDDEN];
    __shared__ float  sb1r[HIDDEN];
    __shared__ float  sW2r[HIDDEN];
    __shared__ float  sb2r;
    __shared__ float  sh[64 * 17];           // h[64 rxns][16+1 pad]

    const int t = threadIdx.x;
    const int w = t >> 6, l = t & 63;
    const int half = l >> 5, j = l & 31;

    // stage weights
    for (int i = t; i < HIDDEN * MSG_DIM; i += 512) sW2m[i] = W2m[i];
    for (int i = t; i < MSG_DIM * HIDDEN; i += 512) sW1r[i] = W1r[i];
    if (t < MSG_DIM) sb2m[t] = b2m[t];
    if (t < HIDDEN) sb1r[t] = b1r[t];
    if (t >= 64 && t < 64 + HIDDEN) sW2r[t - 64] = W2r[t - 64];
    if (t == 128) sb2r = b2r[0];
    for (int i = t; i < 64 * 33; i += 512) sth[i] = 0.0f;
    __syncthreads();

    // per-lane W1 column (registers, loaded once)
    const float w1x = W1m[j];
    const float w1y = W1m[HIDDEN + j];
    const float w1b = b1m[j];

    const int b = blockIdx.x;
    const int beg = base[b];
    const int len = tot[b];

    // half-wave segment [hb, he)
    const int k16 = (w << 1) + half;
    const int hb = beg + ((len * k16) >> 4);
    const int he = beg + ((len * (k16 + 1)) >> 4);

#define PROC(ev, cond)                                                        \
    do {                                                                      \
        if (cond) {                                                           \
            const int r_ = __float_as_int((ev).y) & 63;                       \
            const float z_ = fmaf((ev).x, w1x, fmaf((ev).y, w1y, w1b));       \
            atomicAdd(&sth[r_ * 33 + j], fast_tanh(z_));                      \
            if (j == 0) atomicAdd(&sth[r_ * 33 + 32], 1.0f);                  \
        }                                                                     \
    } while (0)

    if (hb < he) {
        const int hl = he - 1;
        int e = hb;
        float2 n0 = pxs[e];
        float2 n1 = pxs[min(e + 1, hl)];
        float2 n2 = pxs[min(e + 2, hl)];
        float2 n3 = pxs[min(e + 3, hl)];
        for (; e < he; e += 4) {
            const float2 c0 = n0, c1 = n1, c2 = n2, c3 = n3;
            const int en = e + 4;
            if (en < he) {
                n0 = pxs[en];
                n1 = pxs[min(en + 1, hl)];
                n2 = pxs[min(en + 2, hl)];
                n3 = pxs[min(en + 3, hl)];
            }
            PROC(c0, true);
            PROC(c1, e + 1 < he);
            PROC(c2, e + 2 < he);
            PROC(c3, e + 3 < he);
        }
    }
#undef PROC
    __syncthreads();

    // stage A: h[r][d] = cnt[r]*b2m[d] + sum_j sth[r][j] * W2m[j][d]
    // 512 threads: r = t&63, dim-pair g = (t>>6)*2.
    {
        const int r = t & 63, g = (t >> 6) << 1;
        const float cntf = sth[r * 33 + 32];
        float h0 = cntf * sb2m[g + 0], h1 = cntf * sb2m[g + 1];
#pragma unroll 8
        for (int jj = 0; jj < HIDDEN; ++jj) {
            const float ts = sth[r * 33 + jj];
            h0 = fmaf(ts, sW2m[jj * MSG_DIM + g + 0], h0);
            h1 = fmaf(ts, sW2m[jj * MSG_DIM + g + 1], h1);
        }
        sh[r * 17 + g + 0] = h0;
        sh[r * 17 + g + 1] = h1;
    }
    __syncthreads();

    // stage B: rate MLP; thread t (<64) owns reaction b*64+t
    if (t < 64) {
        const int r = b * 64 + t;
        if (r < N_RXN) {
            float h[MSG_DIM];
#pragma unroll
            for (int d = 0; d < MSG_DIM; ++d) h[d] = sh[t * 17 + d];
            float acc2 = sb2r;
#pragma unroll 2
            for (int jj = 0; jj < HIDDEN; ++jj) {
                float z = sb1r[jj];
#pragma unroll
                for (int d = 0; d < MSG_DIM; ++d)
                    z = fmaf(h[d], sW1r[d * HIDDEN + jj], z);
                acc2 = fmaf(fast_tanh(z), sW2r[jj], acc2);
            }
            v[r] = fmaxf(acc2, 0.0f) + log1pf(expf(-fabsf(acc2)));
        }
    }
}

// ---- Phase 2: dxdt via metabolite-bucket binning ----------------------------

__global__ __launch_bounds__(1024) void hist_all_kernel(
    const int* __restrict__ met_all, int* __restrict__ hist)
{
    __shared__ int hb[NBKT_A];
    const int t = threadIdx.x, bk = blockIdx.x;
    for (int i = t; i < NBKT_A; i += 1024) hb[i] = 0;
    __syncthreads();
#pragma unroll
    for (int k = 0; k < 2; ++k) {
        const int i = bk * 2048 + (k << 10) + t;
        if (i < E_ALL / 4) {
            const int4 m = ((const int4*)met_all)[i];
            atomicAdd(&hb[m.x >> 8], 1);
            atomicAdd(&hb[m.y >> 8], 1);
            atomicAdd(&hb[m.z >> 8], 1);
            atomicAdd(&hb[m.w >> 8], 1);
        }
    }
    __syncthreads();
    for (int i2 = t; i2 < NBKT_A; i2 += 1024) hist[bk * NBKT_A + i2] = hb[i2];
}

// counting-sort scatter (8192-edge tile): payload c with met&255 packed into
// its low 8 mantissa bits (rel err ~3e-5; threshold 0.56). Runs copied out
// as contiguous coalesced bursts.
__global__ __launch_bounds__(1024) void scatter_bin_kernel(
    const float* __restrict__ sto_all, const float* __restrict__ v,
    const int* __restrict__ met_all, const int* __restrict__ rxn_all,
    const int* __restrict__ hist, const int* __restrict__ base,
    float* __restrict__ pc)
{
    __shared__ float sp[8192];           // sorted payloads (32 KB)
    __shared__ int cnt[NBKT_A];
    __shared__ int loff[NBKT_A + 1];
    __shared__ int goff[NBKT_A];
    const int t = threadIdx.x, bk = blockIdx.x;
    for (int i = t; i < NBKT_A; i += 1024) {
        cnt[i] = 0;
        goff[i] = hist[bk * NBKT_A + i] + base[i];
    }
    __syncthreads();

    float pay[8]; int meta[8];
    const int e0 = bk * 8192;
#pragma unroll
    for (int k = 0; k < 8; ++k) {
        const int e = e0 + (k << 10) + t;
        if (e < E_ALL) {
            const int m = met_all[e];
            const float c = sto_all[e] * v[rxn_all[e]];
            const int cb = (__float_as_int(c) & ~255) | (m & 255);
            pay[k] = __int_as_float(cb);
            const int q = m >> 8;
            meta[k] = (atomicAdd(&cnt[q], 1) << 9) | q;    // rank<=8191, q<512
        } else meta[k] = -1;
    }
    __syncthreads();

    // single-wave exclusive scan of cnt[391] -> loff
    if (t < 64) {
        int carry = 0;
        for (int bb = 0; bb < NBKT_A; bb += 64) {
            const int idx = bb + t;
            const int val = (idx < NBKT_A) ? cnt[idx] : 0;
            int x = val;
#pragma unroll
            for (int off = 1; off < 64; off <<= 1) {
                const int y = __shfl_up(x, off);
                if (t >= off) x += y;
            }
            if (idx < NBKT_A) loff[idx] = carry + x - val;
            carry += __shfl(x, 63);
        }
        if (t == 0) loff[NBKT_A] = carry;
    }
    __syncthreads();

#pragma unroll
    for (int k = 0; k < 8; ++k) {
        if (meta[k] >= 0)
            sp[loff[meta[k] & 511] + (meta[k] >> 9)] = pay[k];
    }
    __syncthreads();

    // copy-out: wave w handles runs q = w, w+16, ... (coalesced bursts)
    const int w = t >> 6, lane = t & 63;
    for (int q = w; q < NBKT_A; q += 16) {
        const int s = loff[q], lenq = loff[q + 1] - s, d = goff[q];
        for (int i = lane; i < lenq; i += 64)
            pc[d + i] = sp[s + i];
    }
}

// 512 threads: 391 blocks x 8 waves all co-resident (no straggler round).
__global__ __launch_bounds__(512) void bucket_accum_kernel(
    const float* __restrict__ pc,
    const int* __restrict__ base, const int* __restrict__ tot,
    float* __restrict__ dxdt)
{
    __shared__ float acc[256];
    const int b = blockIdx.x, t = threadIdx.x;
    if (t < 256) acc[t] = 0.0f;
    __syncthreads();
    const int beg = base[b];
    const int end = beg + tot[b];
    for (int i = beg + t; i < end; i += 512) {
        const float pv = pc[i];
        atomicAdd(&acc[__float_as_int(pv) & 255], pv);
    }
    __syncthreads();
    if (t < 256) {
        const int met = b * 256 + t;
        if (met < N_MET) dxdt[met] = acc[t];
    }
}

extern "C" void kernel_launch(void* const* d_in, const int* in_sizes, int n_in,
                              void* d_out, int out_size, void* d_ws, size_t ws_size,
                              hipStream_t stream) {
    const float* x_met   = (const float*)d_in[0];
    const float* sto_sub = (const float*)d_in[1];
    const float* sto_all = (const float*)d_in[2];
    const float* W1m     = (const float*)d_in[3];
    const float* b1m     = (const float*)d_in[4];
    const float* W2m     = (const float*)d_in[5];
    const float* b2m     = (const float*)d_in[6];
    const float* W1r     = (const float*)d_in[7];
    const float* b1r     = (const float*)d_in[8];
    const float* W2r     = (const float*)d_in[9];
    const float* b2r     = (const float*)d_in[10];
    const int*   met_sub = (const int*)d_in[11];
    const int*   rxn_sub = (const int*)d_in[12];
    const int*   met_all = (const int*)d_in[13];
    const int*   rxn_all = (const int*)d_in[14];

    float* dxdt = (float*)d_out;             // [N_MET]
    float* v    = dxdt + N_MET;              // [N_RXN]

    // workspace layout. histA shared by both phases; payload region shared:
    // pxs (16 MB, dead after bucket_msg) aliases pc (16 MB, written strictly
    // later in stream order). No memsets needed anywhere.
    const size_t HIST_ELEMS =
        ((size_t)NB_SUB * NBKT_S > (size_t)NB_ALL * NBKT_A)
            ? (size_t)NB_SUB * NBKT_S : (size_t)NB_ALL * NBKT_A;
    char* ws = (char*)d_ws;
    int* histA  = (int*)ws;  ws += ((HIST_ELEMS * 4 + 15) / 16) * 16;
    int* tot_s  = (int*)ws;  ws += ((sizeof(int) * NBKT_S + 15) / 16) * 16;
    int* base_s = (int*)ws;  ws += ((sizeof(int) * NBKT_S + 15) / 16) * 16;
    int* tot_a  = (int*)ws;  ws += ((sizeof(int) * NBKT_A + 15) / 16) * 16;
    int* base_a = (int*)ws;  ws += ((sizeof(int) * NBKT_A + 15) / 16) * 16;
    char* P = ws;                                     // payload union, 16 MB
    float2* pxs = (float2*)P;                         // [E_SUB]  16 MB
    float*  pc  = (float*)P;                          // [E_ALL]  16 MB

    // phase 1: v
    hist_sub_kernel<<<NB_SUB, 1024, 0, stream>>>(rxn_sub, histA);
    scan_cols_kernel<<<NBKT_S, 256, 0, stream>>>(histA, tot_s, NB_SUB, NBKT_S);
    scan_base_kernel<<<1, 256, 0, stream>>>(tot_s, base_s, NBKT_S);
    scatter_bin_sub_kernel<<<NB_SUB, 1024, 0, stream>>>(
        x_met, sto_sub, met_sub, rxn_sub, histA, base_s, pxs);
    bucket_msg_kernel<<<NBKT_S, 512, 0, stream>>>(
        pxs, base_s, tot_s, W1m, b1m, W2m, b2m, W1r, b1r, W2r, b2r, v);

    // phase 2: dxdt
    hist_all_kernel<<<NB_ALL, 1024, 0, stream>>>(met_all, histA);
    scan_cols_kernel<<<NBKT_A, 256, 0, stream>>>(histA, tot_a, NB_ALL, NBKT_A);
    scan_base_kernel<<<1, 256, 0, stream>>>(tot_a, base_a, NBKT_A);
    scatter_bin_kernel<<<NB_ALL, 1024, 0, stream>>>(
        sto_all, v, met_all, rxn_all, histA, base_a, pc);
    bucket_accum_kernel<<<NBKT_A, 512, 0, stream>>>(pc, base_a, tot_a, dxdt);
}

// Round 6
// 272.038 us; speedup vs baseline: 2.4845x; 2.4845x over previous
//
#include <hip/hip_runtime.h>

#define N_MET 100000
#define N_RXN 50000
#define E_SUB 2000000
#define E_ALL 4000000
#define MSG_DIM 16
#define HIDDEN 32

// dxdt-side binning: buckets of 256 metabolites, 8192-edge tiles.
#define NBKT_A 391            // ceil(100000/256)
#define NB_ALL 489            // ceil(4000000/8192)
// v-side binning: buckets of 64 reactions, 8192-edge tiles.
#define NBKT_S 782            // ceil(50000/64)
#define NB_SUB 245            // ceil(2000000/8192)

// HW model (R1-R18): scattered GLOBAL atomics = ~19-20 G ops/s wall.
// R13/R17: ANY per-edge latency-chain design (sequential LDS atomics, or
// per-edge broadcast loads) lands at ~450us with VALU<9% — latency-bound,
// unfixable by instruction reduction. R14/R15: in-LDS counting sort +
// atomic-free register reduce + coalesced burst copy-out is the proven
// structure (bucket_msg 47.9us @ R3 config: chunk 4096, 51KB, ILP2).
// R16: LDS-size/occupancy packing = no effect (37% pinned, not LDS-limited).
// R18 (this round): revert bucket_msg to R3 exact; merge the 5 independent
// hist/scan launches into 3 (hist_all has NO phase-1 dependency) — 10
// launches -> 7, merged kernels fill the machine instead of dribbling.

__device__ __forceinline__ float fast_tanh(float x) {
    // tanh(x) = sign(x) * (1 - 2/(e^{2|x|}+1)); branch-free, v_exp+v_rcp.
    const float ax = fabsf(x);
    const float e = __expf(2.0f * ax);
    const float t = 1.0f - 2.0f * __builtin_amdgcn_rcpf(e + 1.0f);
    return copysignf(t, x);
}

// ---- merged histograms (phase 1 + phase 2 have no cross-dependency) ---------

__global__ __launch_bounds__(1024) void hist_pair_kernel(
    const int* __restrict__ rxn_sub, const int* __restrict__ met_all,
    int* __restrict__ histS, int* __restrict__ histA)
{
    __shared__ int hb[NBKT_S];
    const int t = threadIdx.x, bk = blockIdx.x;
    if (bk < NB_SUB) {
        for (int i = t; i < NBKT_S; i += 1024) hb[i] = 0;
        __syncthreads();
#pragma unroll
        for (int k = 0; k < 2; ++k) {
            const int i = bk * 2048 + (k << 10) + t;
            if (i < E_SUB / 4) {
                const int4 r = ((const int4*)rxn_sub)[i];
                atomicAdd(&hb[r.x >> 6], 1);
                atomicAdd(&hb[r.y >> 6], 1);
                atomicAdd(&hb[r.z >> 6], 1);
                atomicAdd(&hb[r.w >> 6], 1);
            }
        }
        __syncthreads();
        for (int i = t; i < NBKT_S; i += 1024) histS[bk * NBKT_S + i] = hb[i];
    } else {
        const int ba = bk - NB_SUB;
        for (int i = t; i < NBKT_A; i += 1024) hb[i] = 0;
        __syncthreads();
#pragma unroll
        for (int k = 0; k < 2; ++k) {
            const int i = ba * 2048 + (k << 10) + t;
            if (i < E_ALL / 4) {
                const int4 m = ((const int4*)met_all)[i];
                atomicAdd(&hb[m.x >> 8], 1);
                atomicAdd(&hb[m.y >> 8], 1);
                atomicAdd(&hb[m.z >> 8], 1);
                atomicAdd(&hb[m.w >> 8], 1);
            }
        }
        __syncthreads();
        for (int i = t; i < NBKT_A; i += 1024) histA[ba * NBKT_A + i] = hb[i];
    }
}

// ---- merged column scans ----------------------------------------------------

__global__ __launch_bounds__(256) void scan_cols_pair_kernel(
    int* __restrict__ histS, int* __restrict__ histA,
    int* __restrict__ tot_s, int* __restrict__ tot_a)
{
    __shared__ int wsum[4];
    int* hist; int* tot; int nblocks, nbkt, b;
    if ((int)blockIdx.x < NBKT_S) {
        hist = histS; tot = tot_s; nblocks = NB_SUB; nbkt = NBKT_S;
        b = blockIdx.x;
    } else {
        hist = histA; tot = tot_a; nblocks = NB_ALL; nbkt = NBKT_A;
        b = blockIdx.x - NBKT_S;
    }
    const int t = threadIdx.x, lane = t & 63, w = t >> 6;
    int carry = 0;
    for (int basei = 0; basei < nblocks; basei += 256) {
        const int bk = basei + t;
        const int val = (bk < nblocks) ? hist[(size_t)bk * nbkt + b] : 0;
        int x = val;
#pragma unroll
        for (int off = 1; off < 64; off <<= 1) {
            const int y = __shfl_up(x, off);
            if (lane >= off) x += y;
        }
        if (lane == 63) wsum[w] = x;
        __syncthreads();
        if (w == 0) {
            int s = (lane < 4) ? wsum[lane] : 0;
#pragma unroll
            for (int off = 1; off < 4; off <<= 1) {
                const int y = __shfl_up(s, off);
                if (lane >= off) s += y;
            }
            if (lane < 4) wsum[lane] = s;
        }
        __syncthreads();
        const int excl = carry + ((w > 0) ? wsum[w - 1] : 0) + x - val;
        if (bk < nblocks) hist[(size_t)bk * nbkt + b] = excl;
        carry += wsum[3];
        __syncthreads();
    }
    if (t == 0) tot[b] = carry;
}

__global__ __launch_bounds__(256) void scan_base_pair_kernel(
    const int* __restrict__ tot_s, int* __restrict__ base_s,
    const int* __restrict__ tot_a, int* __restrict__ base_a)
{
    __shared__ int wsum[4];
    const int* tot; int* base; int nbkt;
    if (blockIdx.x == 0) { tot = tot_s; base = base_s; nbkt = NBKT_S; }
    else                 { tot = tot_a; base = base_a; nbkt = NBKT_A; }
    const int t = threadIdx.x, lane = t & 63, w = t >> 6;
    int carry = 0;
    for (int basei = 0; basei < nbkt; basei += 256) {
        const int i = basei + t;
        const int val = (i < nbkt) ? tot[i] : 0;
        int x = val;
#pragma unroll
        for (int off = 1; off < 64; off <<= 1) {
            const int y = __shfl_up(x, off);
            if (lane >= off) x += y;
        }
        if (lane == 63) wsum[w] = x;
        __syncthreads();
        if (w == 0) {
            int s = (lane < 4) ? wsum[lane] : 0;
#pragma unroll
            for (int off = 1; off < 4; off <<= 1) {
                const int y = __shfl_up(s, off);
                if (lane >= off) s += y;
            }
            if (lane < 4) wsum[lane] = s;
        }
        __syncthreads();
        const int excl = carry + ((w > 0) ? wsum[w - 1] : 0) + x - val;
        if (i < nbkt) base[i] = excl;
        carry += wsum[3];
        __syncthreads();
    }
}

// ---- Phase 1: v -------------------------------------------------------------

// counting-sort scatter (8192-edge tile): rank via LDS atomic, single-wave
// scan, LDS sort, then per-bucket runs copied out as contiguous bursts.
// payload {x, s'} where s' carries rxn&63 in its low 6 mantissa bits.
__global__ __launch_bounds__(1024) void scatter_bin_sub_kernel(
    const float* __restrict__ x_met, const float* __restrict__ sto_sub,
    const int* __restrict__ met_sub, const int* __restrict__ rxn_sub,
    const int* __restrict__ hist, const int* __restrict__ base,
    float2* __restrict__ pxs)
{
    __shared__ float2 se[8192];          // sorted payloads (64 KB)
    __shared__ int cnt[NBKT_S];
    __shared__ int loff[NBKT_S + 1];
    __shared__ int goff[NBKT_S];
    const int t = threadIdx.x, bk = blockIdx.x;
    for (int i = t; i < NBKT_S; i += 1024) {
        cnt[i] = 0;
        goff[i] = hist[bk * NBKT_S + i] + base[i];
    }
    __syncthreads();

    float2 pay[8]; int meta[8];
    const int e0 = bk * 8192;
#pragma unroll
    for (int k = 0; k < 8; ++k) {
        const int e = e0 + (k << 10) + t;
        if (e < E_SUB) {
            const int r = rxn_sub[e];
            const float x = x_met[met_sub[e]];
            const int sb = (__float_as_int(sto_sub[e]) & ~63) | (r & 63);
            pay[k] = make_float2(x, __int_as_float(sb));
            const int q = r >> 6;
            meta[k] = (atomicAdd(&cnt[q], 1) << 10) | q;   // rank<=8191, q<1024
        } else meta[k] = -1;
    }
    __syncthreads();

    // single-wave exclusive scan of cnt[782] -> loff (no barriers needed)
    if (t < 64) {
        int carry = 0;
        for (int bb = 0; bb < NBKT_S; bb += 64) {
            const int idx = bb + t;
            const int val = (idx < NBKT_S) ? cnt[idx] : 0;
            int x = val;
#pragma unroll
            for (int off = 1; off < 64; off <<= 1) {
                const int y = __shfl_up(x, off);
                if (t >= off) x += y;
            }
            if (idx < NBKT_S) loff[idx] = carry + x - val;
            carry += __shfl(x, 63);
        }
        if (t == 0) loff[NBKT_S] = carry;
    }
    __syncthreads();

#pragma unroll
    for (int k = 0; k < 8; ++k) {
        if (meta[k] >= 0)
            se[loff[meta[k] & 1023] + (meta[k] >> 10)] = pay[k];
    }
    __syncthreads();

    // copy-out: wave w handles runs q = w, w+16, ... (coalesced bursts)
    const int w = t >> 6, lane = t & 63;
    for (int q = w; q < NBKT_S; q += 16) {
        const int s = loff[q], lenq = loff[q + 1] - s, d = goff[q];
        for (int i = lane; i < lenq; i += 64)
            pxs[d + i] = se[s + i];
    }
}

// one block (512 thr, 8 waves) per bucket of 64 reactions. R3-proven config.
// Chunk of <=4096 edges: counting-sort by rxn in LDS (1 rank-atomic/edge),
// then wave w reduces reactions w*8..w*8+7 as 4 pairs: lane half = which
// rxn of the pair, j = lane&31 = hidden dim. Broadcast ds_read of the run's
// edges, register-accumulated tanh sums, one ds_write per (r,j). Epilogue:
// W2m matmul (linearity of segment_sum) + rate MLP.
__global__ __launch_bounds__(512, 6) void bucket_msg_kernel(
    const float2* __restrict__ pxs,
    const int* __restrict__ base, const int* __restrict__ tot,
    const float* __restrict__ W1m, const float* __restrict__ b1m,
    const float* __restrict__ W2m, const float* __restrict__ b2m,
    const float* __restrict__ W1r, const float* __restrict__ b1r,
    const float* __restrict__ W2r, const float* __restrict__ b2r,
    float* __restrict__ v)
{
    __shared__ float2 se[4096];              // sorted edges (32 KB)
    __shared__ float  sth[64 * 33];          // tanh sums [rxn][j], stride 33
    __shared__ int    cnt[64];               // per-chunk run lengths
    __shared__ int    soff[65];              // per-chunk run offsets
    __shared__ int    ccnt[64];              // total edge count per rxn
    __shared__ float  sW2m[HIDDEN * MSG_DIM];
    __shared__ float  sb2m[MSG_DIM];
    __shared__ float  sW1r[MSG_DIM * HIDDEN];
    __shared__ float  sb1r[HIDDEN];
    __shared__ float  sW2r[HIDDEN];
    __shared__ float  sb2r;
    __shared__ float  sh[64 * 17];           // h[64 rxns][16+1 pad]

    const int t = threadIdx.x;
    const int w = t >> 6, l = t & 63;
    const int half = l >> 5, j = l & 31;

    // stage weights
    for (int i = t; i < HIDDEN * MSG_DIM; i += 512) sW2m[i] = W2m[i];
    for (int i = t; i < MSG_DIM * HIDDEN; i += 512) sW1r[i] = W1r[i];
    if (t < MSG_DIM) sb2m[t] = b2m[t];
    if (t < HIDDEN) sb1r[t] = b1r[t];
    if (t >= 64 && t < 64 + HIDDEN) sW2r[t - 64] = W2r[t - 64];
    if (t == 128) sb2r = b2r[0];
    if (t < 64) ccnt[t] = 0;

    // per-lane W1 column (registers, loaded once)
    const float w1x = W1m[j];
    const float w1y = W1m[HIDDEN + j];
    const float w1b = b1m[j];

    const int b = blockIdx.x;
    const int beg = base[b];
    const int end = beg + tot[b];

    float acc[4] = {0.0f, 0.0f, 0.0f, 0.0f};   // per (pair) tanh sums

    for (int cb = beg; cb < end; cb += 4096) {
        if (t < 64) cnt[t] = 0;
        __syncthreads();

        // load + rank (counting-sort pass 1)
        float2 pay[8];
        int meta[8];
#pragma unroll
        for (int k = 0; k < 8; ++k) {
            const int idx = cb + t + (k << 9);
            if (idx < end) {
                const float2 pv = pxs[idx];
                const int r = __float_as_int(pv.y) & 63;
                meta[k] = (atomicAdd(&cnt[r], 1) << 6) | r;
                pay[k] = pv;
            } else meta[k] = -1;
        }
        __syncthreads();

        // scan 64 bins (wave 0)
        if (t < 64) {
            const int orig = cnt[t];
            int x = orig;
#pragma unroll
            for (int off = 1; off < 64; off <<= 1) {
                const int y = __shfl_up(x, off);
                if (t >= off) x += y;
            }
            soff[t] = x - orig;           // exclusive
            if (t == 63) soff[64] = x;    // chunk total
            ccnt[t] += orig;
        }
        __syncthreads();

        // scatter into sorted order (pass 2)
#pragma unroll
        for (int k = 0; k < 8; ++k) {
            if (meta[k] >= 0)
                se[soff[meta[k] & 63] + (meta[k] >> 6)] = pay[k];
        }
        __syncthreads();

        // atomic-free reduce: wave w owns rxns w*8..w*8+7 as 4 pairs
#pragma unroll
        for (int p = 0; p < 4; ++p) {
            const int q = (w << 3) + (p << 1) + half;
            const int rb = soff[q];
            const int rl = soff[q + 1] - rb;
            float a0 = 0.0f, a1 = 0.0f;
            int i = 0;
            for (; i + 2 <= rl; i += 2) {
                const float2 e0 = se[rb + i];
                const float2 e1 = se[rb + i + 1];
                a0 += fast_tanh(fmaf(e0.x, w1x, fmaf(e0.y, w1y, w1b)));
                a1 += fast_tanh(fmaf(e1.x, w1x, fmaf(e1.y, w1y, w1b)));
            }
            if (i < rl) {
                const float2 e0 = se[rb + i];
                a0 += fast_tanh(fmaf(e0.x, w1x, fmaf(e0.y, w1y, w1b)));
            }
            acc[p] += a0 + a1;
        }
        __syncthreads();   // protect cnt/soff/se before next chunk
    }

    // write tanh sums: unique owner per (rxn, j) — plain stores, stride 33
    // makes banks (q + j) % 32 all distinct within a wave row.
#pragma unroll
    for (int p = 0; p < 4; ++p) {
        const int q = (w << 3) + (p << 1) + half;
        sth[q * 33 + j] = acc[p];
    }
    __syncthreads();

    // stage A: h[r][d] = cnt[r]*b2m[d] + sum_j sth[r][j] * W2m[j][d]
    // 512 threads: r = t&63, dim-pair g = (t>>6)*2.
    {
        const int r = t & 63, g = (t >> 6) << 1;
        const float cntf = (float)ccnt[r];
        float h0 = cntf * sb2m[g + 0], h1 = cntf * sb2m[g + 1];
#pragma unroll 8
        for (int jj = 0; jj < HIDDEN; ++jj) {
            const float ts = sth[r * 33 + jj];
            h0 = fmaf(ts, sW2m[jj * MSG_DIM + g + 0], h0);
            h1 = fmaf(ts, sW2m[jj * MSG_DIM + g + 1], h1);
        }
        sh[r * 17 + g + 0] = h0;
        sh[r * 17 + g + 1] = h1;
    }
    __syncthreads();

    // stage B: rate MLP; thread t (<64) owns reaction b*64+t
    if (t < 64) {
        const int r = b * 64 + t;
        if (r < N_RXN) {
            float h[MSG_DIM];
#pragma unroll
            for (int d = 0; d < MSG_DIM; ++d) h[d] = sh[t * 17 + d];
            float acc2 = sb2r;
#pragma unroll 2
            for (int jj = 0; jj < HIDDEN; ++jj) {
                float z = sb1r[jj];
#pragma unroll
                for (int d = 0; d < MSG_DIM; ++d)
                    z = fmaf(h[d], sW1r[d * HIDDEN + jj], z);
                acc2 = fmaf(fast_tanh(z), sW2r[jj], acc2);
            }
            v[r] = fmaxf(acc2, 0.0f) + log1pf(expf(-fabsf(acc2)));
        }
    }
}

// ---- Phase 2: dxdt ----------------------------------------------------------

// counting-sort scatter (8192-edge tile): payload c with met&255 packed into
// its low 8 mantissa bits (rel err ~3e-5; threshold 0.56). Runs copied out
// as contiguous coalesced bursts.
__global__ __launch_bounds__(1024) void scatter_bin_kernel(
    const float* __restrict__ sto_all, const float* __restrict__ v,
    const int* __restrict__ met_all, const int* __restrict__ rxn_all,
    const int* __restrict__ hist, const int* __restrict__ base,
    float* __restrict__ pc)
{
    __shared__ float sp[8192];           // sorted payloads (32 KB)
    __shared__ int cnt[NBKT_A];
    __shared__ int loff[NBKT_A + 1];
    __shared__ int goff[NBKT_A];
    const int t = threadIdx.x, bk = blockIdx.x;
    for (int i = t; i < NBKT_A; i += 1024) {
        cnt[i] = 0;
        goff[i] = hist[bk * NBKT_A + i] + base[i];
    }
    __syncthreads();

    float pay[8]; int meta[8];
    const int e0 = bk * 8192;
#pragma unroll
    for (int k = 0; k < 8; ++k) {
        const int e = e0 + (k << 10) + t;
        if (e < E_ALL) {
            const int m = met_all[e];
            const float c = sto_all[e] * v[rxn_all[e]];
            const int cb = (__float_as_int(c) & ~255) | (m & 255);
            pay[k] = __int_as_float(cb);
            const int q = m >> 8;
            meta[k] = (atomicAdd(&cnt[q], 1) << 9) | q;    // rank<=8191, q<512
        } else meta[k] = -1;
    }
    __syncthreads();

    // single-wave exclusive scan of cnt[391] -> loff
    if (t < 64) {
        int carry = 0;
        for (int bb = 0; bb < NBKT_A; bb += 64) {
            const int idx = bb + t;
            const int val = (idx < NBKT_A) ? cnt[idx] : 0;
            int x = val;
#pragma unroll
            for (int off = 1; off < 64; off <<= 1) {
                const int y = __shfl_up(x, off);
                if (t >= off) x += y;
            }
            if (idx < NBKT_A) loff[idx] = carry + x - val;
            carry += __shfl(x, 63);
        }
        if (t == 0) loff[NBKT_A] = carry;
    }
    __syncthreads();

#pragma unroll
    for (int k = 0; k < 8; ++k) {
        if (meta[k] >= 0)
            sp[loff[meta[k] & 511] + (meta[k] >> 9)] = pay[k];
    }
    __syncthreads();

    // copy-out: wave w handles runs q = w, w+16, ... (coalesced bursts)
    const int w = t >> 6, lane = t & 63;
    for (int q = w; q < NBKT_A; q += 16) {
        const int s = loff[q], lenq = loff[q + 1] - s, d = goff[q];
        for (int i = lane; i < lenq; i += 64)
            pc[d + i] = sp[s + i];
    }
}

// 512 threads: 391 blocks x 8 waves all co-resident (no straggler round).
__global__ __launch_bounds__(512) void bucket_accum_kernel(
    const float* __restrict__ pc,
    const int* __restrict__ base, const int* __restrict__ tot,
    float* __restrict__ dxdt)
{
    __shared__ float acc[256];
    const int b = blockIdx.x, t = threadIdx.x;
    if (t < 256) acc[t] = 0.0f;
    __syncthreads();
    const int beg = base[b];
    const int end = beg + tot[b];
    for (int i = beg + t; i < end; i += 512) {
        const float pv = pc[i];
        atomicAdd(&acc[__float_as_int(pv) & 255], pv);
    }
    __syncthreads();
    if (t < 256) {
        const int met = b * 256 + t;
        if (met < N_MET) dxdt[met] = acc[t];
    }
}

extern "C" void kernel_launch(void* const* d_in, const int* in_sizes, int n_in,
                              void* d_out, int out_size, void* d_ws, size_t ws_size,
                              hipStream_t stream) {
    const float* x_met   = (const float*)d_in[0];
    const float* sto_sub = (const float*)d_in[1];
    const float* sto_all = (const float*)d_in[2];
    const float* W1m     = (const float*)d_in[3];
    const float* b1m     = (const float*)d_in[4];
    const float* W2m     = (const float*)d_in[5];
    const float* b2m     = (const float*)d_in[6];
    const float* W1r     = (const float*)d_in[7];
    const float* b1r     = (const float*)d_in[8];
    const float* W2r     = (const float*)d_in[9];
    const float* b2r     = (const float*)d_in[10];
    const int*   met_sub = (const int*)d_in[11];
    const int*   rxn_sub = (const int*)d_in[12];
    const int*   met_all = (const int*)d_in[13];
    const int*   rxn_all = (const int*)d_in[14];

    float* dxdt = (float*)d_out;             // [N_MET]
    float* v    = dxdt + N_MET;              // [N_RXN]

    // workspace layout. Separate histS/histA (both phases' hist/scan now run
    // up-front, merged). Payload region shared: pxs (16 MB, dead after
    // bucket_msg) aliases pc (16 MB, written strictly later in stream order).
    char* ws = (char*)d_ws;
    int* histS  = (int*)ws;  ws += (((size_t)NB_SUB * NBKT_S * 4 + 15) / 16) * 16;
    int* histA  = (int*)ws;  ws += (((size_t)NB_ALL * NBKT_A * 4 + 15) / 16) * 16;
    int* tot_s  = (int*)ws;  ws += ((sizeof(int) * NBKT_S + 15) / 16) * 16;
    int* base_s = (int*)ws;  ws += ((sizeof(int) * NBKT_S + 15) / 16) * 16;
    int* tot_a  = (int*)ws;  ws += ((sizeof(int) * NBKT_A + 15) / 16) * 16;
    int* base_a = (int*)ws;  ws += ((sizeof(int) * NBKT_A + 15) / 16) * 16;
    char* P = ws;                                     // payload union, 16 MB
    float2* pxs = (float2*)P;                         // [E_SUB]  16 MB
    float*  pc  = (float*)P;                          // [E_ALL]  16 MB

    // merged hist + scans (phase 2 hist has no dependency on phase 1)
    hist_pair_kernel<<<NB_SUB + NB_ALL, 1024, 0, stream>>>(
        rxn_sub, met_all, histS, histA);
    scan_cols_pair_kernel<<<NBKT_S + NBKT_A, 256, 0, stream>>>(
        histS, histA, tot_s, tot_a);
    scan_base_pair_kernel<<<2, 256, 0, stream>>>(tot_s, base_s, tot_a, base_a);

    // phase 1: v
    scatter_bin_sub_kernel<<<NB_SUB, 1024, 0, stream>>>(
        x_met, sto_sub, met_sub, rxn_sub, histS, base_s, pxs);
    bucket_msg_kernel<<<NBKT_S, 512, 0, stream>>>(
        pxs, base_s, tot_s, W1m, b1m, W2m, b2m, W1r, b1r, W2r, b2r, v);

    // phase 2: dxdt
    scatter_bin_kernel<<<NB_ALL, 1024, 0, stream>>>(
        sto_all, v, met_all, rxn_all, histA, base_a, pc);
    bucket_accum_kernel<<<NBKT_A, 512, 0, stream>>>(pc, base_a, tot_a, dxdt);
}